// Round 3
// baseline (687.314 us; speedup 1.0000x reference)
//
#include <hip/hip_runtime.h>
#include <math.h>

#define RES   128
#define NBINS 1536   // (8*8*4 cells) * 6 faces

// ---------------------------------------------------------------------------
// Bin key = (cell ix0,iy0,iz0, cube face). Face from dominant axis of l —
// normalization is a positive scale, so face/sign tests on raw l are identical.
// ---------------------------------------------------------------------------
__device__ __forceinline__ int query_bin(const float* __restrict__ xyz,
                                         const float* __restrict__ l, int q)
{
    float lx = l[3*q+0], ly = l[3*q+1], lz = l[3*q+2];
    float ax = fabsf(lx), ay = fabsf(ly), az = fabsf(lz);
    bool is_x = (ax >= ay) && (ax >= az);
    bool is_y = (!is_x) && (ay >= az);
    int face = is_x ? (lx >= 0.0f ? 0 : 1)
                    : (is_y ? (ly >= 0.0f ? 2 : 3)
                            : (lz >= 0.0f ? 4 : 5));
    float px = xyz[3*q+0], py = xyz[3*q+1], pz = xyz[3*q+2];
    int ix0 = (int)floorf(fminf(fmaxf(px * 7.0f, 0.0f), 7.0f));
    int iy0 = (int)floorf(fminf(fmaxf(py * 7.0f, 0.0f), 7.0f));
    int iz0 = (int)floorf(fminf(fmaxf(pz * 3.0f, 0.0f), 3.0f));
    return ((ix0 * 8 + iy0) * 4 + iz0) * 6 + face;
}

__global__ __launch_bounds__(256) void k_count(
    const float* __restrict__ xyz, const float* __restrict__ l,
    int n, unsigned* __restrict__ hist)
{
    int q = blockIdx.x * 256 + threadIdx.x;
    if (q >= n) return;
    atomicAdd(&hist[query_bin(xyz, l, q)], 1u);
}

// One block, 256 threads, 6 bins/thread: exclusive scan hist -> cursor.
__global__ __launch_bounds__(256) void k_scan(
    const unsigned* __restrict__ hist, unsigned* __restrict__ cursor)
{
    __shared__ unsigned s[256];
    int t = threadIdx.x;
    unsigned v[6]; unsigned sum = 0;
    #pragma unroll
    for (int k = 0; k < 6; ++k) { v[k] = hist[t*6 + k]; sum += v[k]; }
    s[t] = sum;
    __syncthreads();
    for (int off = 1; off < 256; off <<= 1) {
        unsigned x = (t >= off) ? s[t - off] : 0u;
        __syncthreads();
        s[t] += x;
        __syncthreads();
    }
    unsigned base = s[t] - sum;   // exclusive prefix of this thread's chunk
    #pragma unroll
    for (int k = 0; k < 6; ++k) { cursor[t*6 + k] = base; base += v[k]; }
}

__global__ __launch_bounds__(256) void k_scatter(
    const float* __restrict__ xyz, const float* __restrict__ l,
    int n, unsigned* __restrict__ cursor, unsigned* __restrict__ perm)
{
    int q = blockIdx.x * 256 + threadIdx.x;
    if (q >= n) return;
    unsigned pos = atomicAdd(&cursor[query_bin(xyz, l, q)], 1u);
    perm[pos] = q;
}

// ---------------------------------------------------------------------------
// Main kernel: 4 lanes/query (each lane owns one (ox,oy) corner pair = 2
// probes = 8 taps). Queries are consumed in bin-sorted order via perm, and the
// sorted range is partitioned bijectively across the 8 XCDs (bid%8 = XCD,
// m204 formula) so each bin's ~1.5 MB texture footprint stays in one L2.
// ---------------------------------------------------------------------------
__global__ __launch_bounds__(256) void mel_kernel(
    const float* __restrict__ xyz, const float* __restrict__ l,
    const float* __restrict__ base, float* __restrict__ out,
    const unsigned* __restrict__ perm, int n)
{
    // bijective XCD-chunked block remap (valid for any gridDim)
    int nb  = gridDim.x;
    int b   = blockIdx.x;
    int xcd = b & 7, j = b >> 3;
    int qq  = nb >> 3, r = nb & 7;
    int slot = ((xcd < r) ? (xcd * (qq + 1)) : (r * (qq + 1) + (xcd - r) * qq)) + j;

    int g    = threadIdx.x >> 2;      // query group within block (0..63)
    int sub  = threadIdx.x & 3;       // (ox,oy) corner this lane owns
    int spos = slot * 64 + g;         // sorted position
    if (spos >= n) return;
    int q = perm ? (int)perm[spos] : spos;

    // ---- direction = l / max(||l||, 1e-9) ----
    float lx = l[3*q+0], ly = l[3*q+1], lz = l[3*q+2];
    float nrm = sqrtf(lx*lx + ly*ly + lz*lz);
    float inv = 1.0f / fmaxf(nrm, 1e-9f);
    float dx = lx*inv, dy = ly*inv, dz = lz*inv;

    // ---- cube face / uv (OpenGL convention) ----
    float ax = fabsf(dx), ay = fabsf(dy), az = fabsf(dz);
    bool is_x = (ax >= ay) && (ax >= az);
    bool is_y = (!is_x) && (ay >= az);

    int face;
    float ma, sc, tc;
    if (is_x) {
        face = (dx >= 0.0f) ? 0 : 1;
        ma = ax;
        sc = (dx >= 0.0f) ? -dz : dz;
        tc = -dy;
    } else if (is_y) {
        face = (dy >= 0.0f) ? 2 : 3;
        ma = ay;
        sc = dx;
        tc = (dy >= 0.0f) ? dz : -dz;
    } else {
        face = (dz >= 0.0f) ? 4 : 5;
        ma = az;
        sc = (dz >= 0.0f) ? dx : -dx;
        tc = -dy;
    }
    ma = fmaxf(ma, 1e-9f);
    float u = 0.5f * (sc / ma + 1.0f);
    float v = 0.5f * (tc / ma + 1.0f);

    // ---- bilinear tap coords on the 128x128 face ----
    float fx = u * (float)RES - 0.5f;
    float fy = v * (float)RES - 0.5f;
    float x0f = floorf(fx), y0f = floorf(fy);
    float tx = fx - x0f, ty = fy - y0f;
    int x0 = min(max((int)x0f,     0), RES-1);
    int x1 = min(max((int)x0f + 1, 0), RES-1);
    int y0 = min(max((int)y0f,     0), RES-1);
    int y1 = min(max((int)y0f + 1, 0), RES-1);

    // ---- trilinear probe corners on the (8,8,4) grid, span = 1 ----
    float px = xyz[3*q+0], py = xyz[3*q+1], pz = xyz[3*q+2];
    float cx = fminf(fmaxf(px * 7.0f, 0.0f), 7.0f);
    float cy = fminf(fmaxf(py * 7.0f, 0.0f), 7.0f);
    float cz = fminf(fmaxf(pz * 3.0f, 0.0f), 3.0f);
    int ix0 = (int)floorf(cx), iy0 = (int)floorf(cy), iz0 = (int)floorf(cz);
    int ix1 = min(ix0 + 1, 7), iy1 = min(iy0 + 1, 7), iz1 = min(iz0 + 1, 3);
    float tgx = cx - (float)ix0, tgy = cy - (float)iy0, tgz = cz - (float)iz0;

    int   ox  = sub >> 1, oy = sub & 1;
    float wxf = ox ? tgx : (1.0f - tgx);
    float wyf = oy ? tgy : (1.0f - tgy);
    int   gxi = ox ? ix1 : ix0;
    int   gyi = oy ? iy1 : iy0;
    float wxy = wxf * wyf;
    float pw0 = wxy * (1.0f - tgz);
    float pw1 = wxy * tgz;
    int   gb  = gxi*32 + gyi*4;
    int   p0  = gb + iz0;
    int   p1  = gb + iz1;

    // ---- bilinear weights / tap offsets ----
    int toff[4] = { y0*RES + x0, y0*RES + x1, y1*RES + x0, y1*RES + x1 };
    float bw[4];
    bw[0] = (1.0f - ty) * (1.0f - tx);
    bw[1] = (1.0f - ty) * tx;
    bw[2] = ty * (1.0f - tx);
    bw[3] = ty * tx;

    int face_off = face * (RES * RES);
    const float* bp0 = base + (size_t)(p0 * (6 * RES * RES) + face_off) * 3;
    const float* bp1 = base + (size_t)(p1 * (6 * RES * RES) + face_off) * 3;

    // ---- PHASE 1: issue all 8 gather loads ----
    float v0[4][3], v1[4][3];
    #pragma unroll
    for (int t = 0; t < 4; ++t) {
        const float* a = bp0 + toff[t] * 3;
        v0[t][0] = a[0]; v0[t][1] = a[1]; v0[t][2] = a[2];
    }
    #pragma unroll
    for (int t = 0; t < 4; ++t) {
        const float* a = bp1 + toff[t] * 3;
        v1[t][0] = a[0]; v1[t][1] = a[1]; v1[t][2] = a[2];
    }
    __builtin_amdgcn_sched_barrier(0);

    // ---- PHASE 2: blend ----
    float a0 = 0.0f, a1 = 0.0f, a2 = 0.0f;
    #pragma unroll
    for (int t = 0; t < 4; ++t) {
        float w0 = pw0 * bw[t];
        float w1 = pw1 * bw[t];
        a0 += w0 * v0[t][0] + w1 * v1[t][0];
        a1 += w0 * v0[t][1] + w1 * v1[t][1];
        a2 += w0 * v0[t][2] + w1 * v1[t][2];
    }
    float ws = pw0 + pw1;

    // ---- reduce across the 4-lane group ----
    a0 += __shfl_xor(a0, 1); a1 += __shfl_xor(a1, 1);
    a2 += __shfl_xor(a2, 1); ws += __shfl_xor(ws, 1);
    a0 += __shfl_xor(a0, 2); a1 += __shfl_xor(a1, 2);
    a2 += __shfl_xor(a2, 2); ws += __shfl_xor(ws, 2);

    if (sub == 0) {
        float winv = 1.0f / fmaxf(ws, 1e-8f);
        a0 *= winv; a1 *= winv; a2 *= winv;
        out[3*q+0] = 10.0f / (1.0f + __expf(-a0));
        out[3*q+1] = 10.0f / (1.0f + __expf(-a1));
        out[3*q+2] = 10.0f / (1.0f + __expf(-a2));
    }
}

extern "C" void kernel_launch(void* const* d_in, const int* in_sizes, int n_in,
                              void* d_out, int out_size, void* d_ws, size_t ws_size,
                              hipStream_t stream) {
    const float* xyz  = (const float*)d_in[0];
    const float* l    = (const float*)d_in[1];
    const float* base = (const float*)d_in[2];
    float* out = (float*)d_out;
    int n = in_sizes[0] / 3;

    int qblocks = (n + 63) / 64;              // main: 4 lanes/query, 64 q/block
    int nblocks = (n + 255) / 256;            // count/scatter

    size_t need = (size_t)NBINS * 4 * 2 + (size_t)n * 4;
    if (d_ws != nullptr && ws_size >= need) {
        unsigned* hist   = (unsigned*)d_ws;
        unsigned* cursor = hist + NBINS;
        unsigned* perm   = cursor + NBINS;
        hipMemsetAsync(hist, 0, NBINS * sizeof(unsigned), stream);
        k_count  <<<nblocks, 256, 0, stream>>>(xyz, l, n, hist);
        k_scan   <<<1,       256, 0, stream>>>(hist, cursor);
        k_scatter<<<nblocks, 256, 0, stream>>>(xyz, l, n, cursor, perm);
        mel_kernel<<<qblocks, 256, 0, stream>>>(xyz, l, base, out, perm, n);
    } else {
        mel_kernel<<<qblocks, 256, 0, stream>>>(xyz, l, base, out, nullptr, n);
    }
}

// Round 4
// 485.445 us; speedup vs baseline: 1.4158x; 1.4158x over previous
//
#include <hip/hip_runtime.h>
#include <math.h>

#define RES 128

// ---------------------------------------------------------------------------
// Face-partitioned multi-pass gather, NO workspace (round-3 lesson: touching
// d_ws makes the harness re-poison 1.2 GB per iteration = +185 us, an
// unrecoverable tax). Grid = 6 face-segments x qblocks; blocks dispatch in
// roughly blockIdx order, so the ~2k-block resident window processes one
// 100 MB face-set at a time -> face-set stays LLC-resident (256 MB), re-taps
// become LLC hits, DRAM fetch drops toward the distinct-line floor (~253 MB).
//
// 4 lanes cooperate on one query (round-2 structure, 77% occupancy, VGPR=24):
// each lane owns one (ox,oy) trilinear corner pair = 2 probes = 8 taps.
// Face test on raw l is exact: d = l * inv with inv > 0, and fl() is
// monotone, so all |dx|>=|dy| / sign comparisons match the normalized path.
// ---------------------------------------------------------------------------
__global__ __launch_bounds__(256) void mel_kernel(
    const float* __restrict__ xyz, const float* __restrict__ l,
    const float* __restrict__ base, float* __restrict__ out,
    int n, int qblocks)
{
    int face_sel = blockIdx.x / qblocks;          // 0..5, time-ordered
    int pb       = blockIdx.x - face_sel * qblocks;

    int g   = threadIdx.x >> 2;    // query group within block (0..63)
    int sub = threadIdx.x & 3;     // (ox,oy) corner this lane owns
    int q   = pb * 64 + g;
    if (q >= n) return;

    // ---- raw-l face test for the pass filter (scale-invariant) ----
    float lx = l[3*q+0], ly = l[3*q+1], lz = l[3*q+2];
    {
        float rax = fabsf(lx), ray = fabsf(ly), raz = fabsf(lz);
        bool rx = (rax >= ray) && (rax >= raz);
        bool ry = (!rx) && (ray >= raz);
        int rface = rx ? (lx >= 0.0f ? 0 : 1)
                       : (ry ? (ly >= 0.0f ? 2 : 3)
                             : (lz >= 0.0f ? 4 : 5));
        if (rface != face_sel) return;
    }

    // ---- direction = l / max(||l||, 1e-9) ----
    float nrm = sqrtf(lx*lx + ly*ly + lz*lz);
    float inv = 1.0f / fmaxf(nrm, 1e-9f);
    float dx = lx*inv, dy = ly*inv, dz = lz*inv;

    // ---- cube face / uv (OpenGL convention) ----
    float ax = fabsf(dx), ay = fabsf(dy), az = fabsf(dz);
    bool is_x = (ax >= ay) && (ax >= az);
    bool is_y = (!is_x) && (ay >= az);

    int face;
    float ma, sc, tc;
    if (is_x) {
        face = (dx >= 0.0f) ? 0 : 1;
        ma = ax;
        sc = (dx >= 0.0f) ? -dz : dz;
        tc = -dy;
    } else if (is_y) {
        face = (dy >= 0.0f) ? 2 : 3;
        ma = ay;
        sc = dx;
        tc = (dy >= 0.0f) ? dz : -dz;
    } else {
        face = (dz >= 0.0f) ? 4 : 5;
        ma = az;
        sc = (dz >= 0.0f) ? dx : -dx;
        tc = -dy;
    }
    ma = fmaxf(ma, 1e-9f);
    float u = 0.5f * (sc / ma + 1.0f);
    float v = 0.5f * (tc / ma + 1.0f);

    // ---- bilinear tap coords on the 128x128 face ----
    float fx = u * (float)RES - 0.5f;
    float fy = v * (float)RES - 0.5f;
    float x0f = floorf(fx), y0f = floorf(fy);
    float tx = fx - x0f, ty = fy - y0f;
    int x0 = min(max((int)x0f,     0), RES-1);
    int x1 = min(max((int)x0f + 1, 0), RES-1);
    int y0 = min(max((int)y0f,     0), RES-1);
    int y1 = min(max((int)y0f + 1, 0), RES-1);

    // ---- trilinear probe corners on the (8,8,4) grid, span = 1 ----
    float px = xyz[3*q+0], py = xyz[3*q+1], pz = xyz[3*q+2];
    float cx = fminf(fmaxf(px * 7.0f, 0.0f), 7.0f);
    float cy = fminf(fmaxf(py * 7.0f, 0.0f), 7.0f);
    float cz = fminf(fmaxf(pz * 3.0f, 0.0f), 3.0f);
    int ix0 = (int)floorf(cx), iy0 = (int)floorf(cy), iz0 = (int)floorf(cz);
    int ix1 = min(ix0 + 1, 7), iy1 = min(iy0 + 1, 7), iz1 = min(iz0 + 1, 3);
    float tgx = cx - (float)ix0, tgy = cy - (float)iy0, tgz = cz - (float)iz0;

    // This lane's corner: ox = sub>>1, oy = sub&1; two probes differ in oz.
    int   ox  = sub >> 1, oy = sub & 1;
    float wxf = ox ? tgx : (1.0f - tgx);
    float wyf = oy ? tgy : (1.0f - tgy);
    int   gxi = ox ? ix1 : ix0;
    int   gyi = oy ? iy1 : iy0;
    float wxy = wxf * wyf;
    float pw0 = wxy * (1.0f - tgz);   // probe (gxi,gyi,iz0)
    float pw1 = wxy * tgz;            // probe (gxi,gyi,iz1)
    int   gb  = gxi*32 + gyi*4;
    int   p0  = gb + iz0;
    int   p1  = gb + iz1;

    // ---- bilinear weights / tap offsets ----
    int toff[4] = { y0*RES + x0, y0*RES + x1, y1*RES + x0, y1*RES + x1 };
    float bw[4];
    bw[0] = (1.0f - ty) * (1.0f - tx);
    bw[1] = (1.0f - ty) * tx;
    bw[2] = ty * (1.0f - tx);
    bw[3] = ty * tx;

    int face_off = face * (RES * RES);
    const float* bp0 = base + (size_t)(p0 * (6 * RES * RES) + face_off) * 3;
    const float* bp1 = base + (size_t)(p1 * (6 * RES * RES) + face_off) * 3;

    // ---- PHASE 1: issue all 8 gather loads (all in flight) ----
    float v0[4][3], v1[4][3];
    #pragma unroll
    for (int t = 0; t < 4; ++t) {
        const float* a = bp0 + toff[t] * 3;
        v0[t][0] = a[0]; v0[t][1] = a[1]; v0[t][2] = a[2];
    }
    #pragma unroll
    for (int t = 0; t < 4; ++t) {
        const float* a = bp1 + toff[t] * 3;
        v1[t][0] = a[0]; v1[t][1] = a[1]; v1[t][2] = a[2];
    }
    __builtin_amdgcn_sched_barrier(0);

    // ---- PHASE 2: blend this lane's 2 probes ----
    float a0 = 0.0f, a1 = 0.0f, a2 = 0.0f;
    #pragma unroll
    for (int t = 0; t < 4; ++t) {
        float w0 = pw0 * bw[t];
        float w1 = pw1 * bw[t];
        a0 += w0 * v0[t][0] + w1 * v1[t][0];
        a1 += w0 * v0[t][1] + w1 * v1[t][1];
        a2 += w0 * v0[t][2] + w1 * v1[t][2];
    }
    float ws = pw0 + pw1;

    // ---- reduce across the 4-lane group (xor 1, then 2) ----
    // All 4 lanes of a group take the same branch (same q, same l values),
    // so shfl participants are uniformly active.
    a0 += __shfl_xor(a0, 1); a1 += __shfl_xor(a1, 1);
    a2 += __shfl_xor(a2, 1); ws += __shfl_xor(ws, 1);
    a0 += __shfl_xor(a0, 2); a1 += __shfl_xor(a1, 2);
    a2 += __shfl_xor(a2, 2); ws += __shfl_xor(ws, 2);

    if (sub == 0) {
        float winv = 1.0f / fmaxf(ws, 1e-8f);
        a0 *= winv; a1 *= winv; a2 *= winv;
        out[3*q+0] = 10.0f / (1.0f + __expf(-a0));
        out[3*q+1] = 10.0f / (1.0f + __expf(-a1));
        out[3*q+2] = 10.0f / (1.0f + __expf(-a2));
    }
}

extern "C" void kernel_launch(void* const* d_in, const int* in_sizes, int n_in,
                              void* d_out, int out_size, void* d_ws, size_t ws_size,
                              hipStream_t stream) {
    const float* xyz  = (const float*)d_in[0];
    const float* l    = (const float*)d_in[1];
    const float* base = (const float*)d_in[2];
    float* out = (float*)d_out;
    int n = in_sizes[0] / 3;

    int qblocks = (n + 63) / 64;           // 4 lanes/query, 64 queries/block
    int blocks  = 6 * qblocks;             // 6 time-ordered face segments
    mel_kernel<<<blocks, 256, 0, stream>>>(xyz, l, base, out, n, qblocks);
}